// Round 6
// baseline (651.459 us; speedup 1.0000x reference)
//
#include <hip/hip_runtime.h>
#include <cstdint>

#define N_NODES 100000
#define N_EDGES 3200000
#define BSZ     64                // dst nodes per bucket (single-owner, merge-free)
#define NBUCK   1563              // ceil(N_NODES / 64)
#define NPAD    (NBUCK * BSZ)     // 100032
#define NQUAD   4                 // src quadrants (sub-sort for L2 phase locality)
#define NCELL   (NBUCK * NQUAD)   // 6252
#define QDIV    25000             // src / QDIV -> quadrant
#define K13_BLOCKS 64
#define K13_CHUNK  50000          // 64 * 50000 = 3.2M exactly

// ---- float <-> order-preserving unsigned (signed-float max via uint max) ----
__device__ __forceinline__ unsigned flipf(float f) {
    unsigned u = __float_as_uint(f);
    return (u & 0x80000000u) ? ~u : (u | 0x80000000u);
}
__device__ __forceinline__ float unflipf(unsigned v) {
    unsigned u = (v & 0x80000000u) ? (v & 0x7FFFFFFFu) : ~v;
    return __uint_as_float(u);
}

__device__ __forceinline__ int cell_of(int s, int d) {
    return ((d >> 6) << 2) | (s / QDIV);
}

// ---------------- K1: per-cell edge counts ----------------
__global__ __launch_bounds__(256) void k1_count(const int* __restrict__ ei,
                                                int* __restrict__ total) {
    __shared__ int hist[NCELL];              // 25 KB
    for (int t = threadIdx.x; t < NCELL; t += 256) hist[t] = 0;
    __syncthreads();
    int e0 = blockIdx.x * K13_CHUNK;
    for (int k = threadIdx.x; k < K13_CHUNK; k += 256) {
        int e = e0 + k;
        atomicAdd(&hist[cell_of(ei[e], ei[N_EDGES + e])], 1);
    }
    __syncthreads();
    for (int t = threadIdx.x; t < NCELL; t += 256) {
        int c = hist[t];
        if (c) atomicAdd(&total[t], c);
    }
}

// ---------------- K2: exclusive scan over NCELL -> cellBase, cursor ----------------
__global__ __launch_bounds__(1024) void k2_scan(const int* __restrict__ total,
                                                int* __restrict__ cellBase,
                                                int* __restrict__ cursor) {
    __shared__ int part[1024];
    int t = threadIdx.x;
    int base = t * 8;
    int v[8];
    int s = 0;
#pragma unroll
    for (int j = 0; j < 8; j++) {
        v[j] = (base + j < NCELL) ? total[base + j] : 0;
        s += v[j];
    }
    part[t] = s;
    __syncthreads();
    for (int off = 1; off < 1024; off <<= 1) {
        int u = (t >= off) ? part[t - off] : 0;
        __syncthreads();
        part[t] += u;
        __syncthreads();
    }
    int ex = part[t] - s;
#pragma unroll
    for (int j = 0; j < 8; j++) {
        if (base + j < NCELL) { cellBase[base + j] = ex; cursor[base + j] = ex; }
        ex += v[j];
    }
    if (t == 1023) cellBase[NCELL] = part[1023];
}

// ---------------- K3: scatter edges into cell-contiguous packed records ----------------
// record: int2 { (src<<6) | (dst&63), bits(norm) }
__global__ __launch_bounds__(256) void k3_scatter(const int* __restrict__ ei,
                                                  const float* __restrict__ norm,
                                                  int* __restrict__ cursor,
                                                  int2* __restrict__ ebuf) {
    __shared__ int hist[NCELL];              // 25 KB
    __shared__ int lcur[NCELL];              // 25 KB (claimed base, then bumped)
    for (int t = threadIdx.x; t < NCELL; t += 256) hist[t] = 0;
    __syncthreads();
    int e0 = blockIdx.x * K13_CHUNK;
    for (int k = threadIdx.x; k < K13_CHUNK; k += 256) {
        int e = e0 + k;
        atomicAdd(&hist[cell_of(ei[e], ei[N_EDGES + e])], 1);
    }
    __syncthreads();
    for (int t = threadIdx.x; t < NCELL; t += 256) {
        int c = hist[t];
        lcur[t] = c ? atomicAdd(&cursor[t], c) : 0;
    }
    __syncthreads();
    for (int k = threadIdx.x; k < K13_CHUNK; k += 256) {
        int e = e0 + k;
        int s = ei[e];
        int d = ei[N_EDGES + e];
        float w = norm[e];
        int c = cell_of(s, d);
        int r = atomicAdd(&lcur[c], 1);
        ebuf[r] = make_int2((s << 6) | (d & 63), __float_as_int(w));
    }
}

// -------- K4: layer-1 aggregation (LDS, merge-free) + fused node1 -> h1, z2 --------
// sw layout: w1m_l[0..48) b1m[48..72) w1m_r[72..120) w1x_l[120..136) b1x[136..144)
//            w1x_r[144..160) w2m_l[160..544)
__global__ __launch_bounds__(256) void k4_fused(
        const float2* __restrict__ x, const int2* __restrict__ ebuf,
        const int* __restrict__ cellBase,
        const float* __restrict__ w1m_l, const float* __restrict__ b1m,
        const float* __restrict__ w1m_r,
        const float* __restrict__ w1x_l, const float* __restrict__ b1x,
        const float* __restrict__ w1x_r,
        const float* __restrict__ w2m_l,
        float* __restrict__ h1, float* __restrict__ z2) {
    __shared__ float sw[544];
    __shared__ float    s_sum[2 * BSZ];
    __shared__ unsigned s_max[2 * BSZ];
    for (int t = threadIdx.x; t < 544; t += 256) {
        float v;
        if (t < 48)       v = w1m_l[t];
        else if (t < 72)  v = b1m[t - 48];
        else if (t < 120) v = w1m_r[t - 72];
        else if (t < 136) v = w1x_l[t - 120];
        else if (t < 144) v = b1x[t - 136];
        else if (t < 160) v = w1x_r[t - 144];
        else              v = w2m_l[t - 160];
        sw[t] = v;
    }
    if (threadIdx.x < 2 * BSZ) { s_sum[threadIdx.x] = 0.0f; s_max[threadIdx.x] = 0u; }
    __syncthreads();

    int b = blockIdx.x;
    int beg = cellBase[b * NQUAD], end = cellBase[b * NQUAD + NQUAD];

    int e = beg + threadIdx.x;
    for (; e + 768 < end; e += 1024) {
        int2 r0 = ebuf[e], r1 = ebuf[e + 256], r2 = ebuf[e + 512], r3 = ebuf[e + 768];
        float2 x0 = x[r0.x >> 6], x1 = x[r1.x >> 6], x2 = x[r2.x >> 6], x3 = x[r3.x >> 6];
        float w0 = __int_as_float(r0.y), w1 = __int_as_float(r1.y);
        float w2 = __int_as_float(r2.y), w3 = __int_as_float(r3.y);
        int l0 = (r0.x & 63) * 2, l1 = (r1.x & 63) * 2, l2 = (r2.x & 63) * 2, l3 = (r3.x & 63) * 2;
        atomicAdd(&s_sum[l0],     x0.x * w0); atomicAdd(&s_sum[l0 + 1], x0.y * w0);
        atomicAdd(&s_sum[l1],     x1.x * w1); atomicAdd(&s_sum[l1 + 1], x1.y * w1);
        atomicAdd(&s_sum[l2],     x2.x * w2); atomicAdd(&s_sum[l2 + 1], x2.y * w2);
        atomicAdd(&s_sum[l3],     x3.x * w3); atomicAdd(&s_sum[l3 + 1], x3.y * w3);
        atomicMax(&s_max[l0],     flipf(x0.x)); atomicMax(&s_max[l0 + 1], flipf(x0.y));
        atomicMax(&s_max[l1],     flipf(x1.x)); atomicMax(&s_max[l1 + 1], flipf(x1.y));
        atomicMax(&s_max[l2],     flipf(x2.x)); atomicMax(&s_max[l2 + 1], flipf(x2.y));
        atomicMax(&s_max[l3],     flipf(x3.x)); atomicMax(&s_max[l3 + 1], flipf(x3.y));
    }
    for (; e < end; e += 256) {
        int2 r = ebuf[e];
        float2 xs = x[r.x >> 6];
        float w = __int_as_float(r.y);
        int l = (r.x & 63) * 2;
        atomicAdd(&s_sum[l],     xs.x * w); atomicAdd(&s_sum[l + 1], xs.y * w);
        atomicMax(&s_max[l],     flipf(xs.x)); atomicMax(&s_max[l + 1], flipf(xs.y));
    }
    __syncthreads();

    // node1 epilogue for this block's 64 nodes (threads 0..63)
    int t = threadIdx.x;
    if (t >= BSZ) return;
    int i = b * BSZ + t;
    if (i >= N_NODES) return;

    float2 xi = x[i];
    float a0 = s_sum[2 * t], a1 = s_sum[2 * t + 1];
    unsigned m0u = s_max[2 * t], m1u = s_max[2 * t + 1];
    float m0 = m0u ? unflipf(m0u) : 0.0f;   // 0 sentinel == empty segment -> 0
    float m1 = m1u ? unflipf(m1u) : 0.0f;

    float hh[32];
#pragma unroll
    for (int k = 0; k < 24; k++) {
        float v = sw[48 + k] + sw[2 * k] * a0 + sw[2 * k + 1] * a1
                + sw[72 + 2 * k] * xi.x + sw[72 + 2 * k + 1] * xi.y;
        hh[k] = fmaxf(v, 0.0f);
    }
#pragma unroll
    for (int k = 0; k < 8; k++) {
        float v = sw[136 + k] + sw[120 + 2 * k] * m0 + sw[120 + 2 * k + 1] * m1
                + sw[144 + 2 * k] * xi.x + sw[144 + 2 * k + 1] * xi.y;
        hh[24 + k] = fmaxf(v, 0.0f);
    }

    float4* h1v = (float4*)(h1 + (size_t)i * 32);
#pragma unroll
    for (int q = 0; q < 8; q++)
        h1v[q] = make_float4(hh[4 * q], hh[4 * q + 1], hh[4 * q + 2], hh[4 * q + 3]);

    float zz[12];
#pragma unroll
    for (int j = 0; j < 12; j++) {
        float v = 0.0f;
#pragma unroll
        for (int k = 0; k < 32; k++) v += hh[k] * sw[160 + j * 32 + k];
        zz[j] = v;
    }
    float4* z2v = (float4*)(z2 + (size_t)i * 12);
    z2v[0] = make_float4(zz[0], zz[1], zz[2], zz[3]);
    z2v[1] = make_float4(zz[4], zz[5], zz[6], zz[7]);
    z2v[2] = make_float4(zz[8], zz[9], zz[10], zz[11]);
}

// -------- K5: layer-2 aggregation (LDS, merge-free) + fused node2 + MLP -> out --------
// sw layout: b2m[0..12) w2m_r[12..396) w2x_l[396..524) b2x[524..528) w2x_r[528..656)
//            w3[656..784) b3[784..792) w4[792..832) b4[832..837) w5[837..842) b5[842]
__global__ __launch_bounds__(256) void k5_fused(
        const float* __restrict__ h1, const float* __restrict__ z2g,
        const int2* __restrict__ ebuf, const int* __restrict__ cellBase,
        const float* __restrict__ b2m, const float* __restrict__ w2m_r,
        const float* __restrict__ w2x_l, const float* __restrict__ b2x,
        const float* __restrict__ w2x_r,
        const float* __restrict__ w3, const float* __restrict__ b3,
        const float* __restrict__ w4, const float* __restrict__ b4,
        const float* __restrict__ w5, const float* __restrict__ b5,
        float* __restrict__ out) {
    __shared__ float sw[843];                // 3.4 KB
    __shared__ unsigned s2x[BSZ * 32];       // 8 KB (h1 >= 0 -> uint order == float order)
    __shared__ float    s2s[BSZ * 12];       // 3 KB
    for (int t = threadIdx.x; t < 843; t += 256) {
        float v;
        if (t < 12)       v = b2m[t];
        else if (t < 396) v = w2m_r[t - 12];
        else if (t < 524) v = w2x_l[t - 396];
        else if (t < 528) v = b2x[t - 524];
        else if (t < 656) v = w2x_r[t - 528];
        else if (t < 784) v = w3[t - 656];
        else if (t < 792) v = b3[t - 784];
        else if (t < 832) v = w4[t - 792];
        else if (t < 837) v = b4[t - 832];
        else if (t < 842) v = w5[t - 837];
        else              v = b5[0];
        sw[t] = v;
    }
    for (int t = threadIdx.x; t < BSZ * 32; t += 256) s2x[t] = 0u;
    for (int t = threadIdx.x; t < BSZ * 12; t += 256) s2s[t] = 0.0f;
    __syncthreads();

    int b = blockIdx.x;
    int beg = cellBase[b * NQUAD], end = cellBase[b * NQUAD + NQUAD];

    int f  = threadIdx.x & 31;
    int eg = threadIdx.x >> 5;               // 8 edge-groups per block
    int e = beg + eg;
    for (; e + 24 < end; e += 32) {
        int2 r0 = ebuf[e], r1 = ebuf[e + 8], r2 = ebuf[e + 16], r3 = ebuf[e + 24];
        unsigned v0 = __float_as_uint(h1[(size_t)(r0.x >> 6) * 32 + f]);
        unsigned v1 = __float_as_uint(h1[(size_t)(r1.x >> 6) * 32 + f]);
        unsigned v2 = __float_as_uint(h1[(size_t)(r2.x >> 6) * 32 + f]);
        unsigned v3 = __float_as_uint(h1[(size_t)(r3.x >> 6) * 32 + f]);
        float z0 = 0, z1 = 0, z2v = 0, z3 = 0;
        if (f < 12) {
            z0  = z2g[(size_t)(r0.x >> 6) * 12 + f];
            z1  = z2g[(size_t)(r1.x >> 6) * 12 + f];
            z2v = z2g[(size_t)(r2.x >> 6) * 12 + f];
            z3  = z2g[(size_t)(r3.x >> 6) * 12 + f];
        }
        atomicMax(&s2x[(r0.x & 63) * 32 + f], v0);
        atomicMax(&s2x[(r1.x & 63) * 32 + f], v1);
        atomicMax(&s2x[(r2.x & 63) * 32 + f], v2);
        atomicMax(&s2x[(r3.x & 63) * 32 + f], v3);
        if (f < 12) {
            atomicAdd(&s2s[(r0.x & 63) * 12 + f], z0  * __int_as_float(r0.y));
            atomicAdd(&s2s[(r1.x & 63) * 12 + f], z1  * __int_as_float(r1.y));
            atomicAdd(&s2s[(r2.x & 63) * 12 + f], z2v * __int_as_float(r2.y));
            atomicAdd(&s2s[(r3.x & 63) * 12 + f], z3  * __int_as_float(r3.y));
        }
    }
    for (; e < end; e += 8) {
        int2 r = ebuf[e];
        int src = r.x >> 6, local = r.x & 63;
        unsigned v = __float_as_uint(h1[(size_t)src * 32 + f]);
        atomicMax(&s2x[local * 32 + f], v);
        if (f < 12) {
            float z = z2g[(size_t)src * 12 + f];
            atomicAdd(&s2s[local * 12 + f], z * __int_as_float(r.y));
        }
    }
    __syncthreads();

    // node2 + MLP epilogue for this block's 64 nodes (threads 0..63)
    int t = threadIdx.x;
    if (t >= BSZ) return;
    int i = b * BSZ + t;
    if (i >= N_NODES) return;

    float hh[32], ax[32];
    const float4* h1v = (const float4*)(h1 + (size_t)i * 32);
#pragma unroll
    for (int q = 0; q < 8; q++) {
        float4 a = h1v[q];
        hh[4 * q] = a.x; hh[4 * q + 1] = a.y; hh[4 * q + 2] = a.z; hh[4 * q + 3] = a.w;
    }
#pragma unroll
    for (int k = 0; k < 32; k++) ax[k] = __uint_as_float(s2x[t * 32 + k]);

    float h2[16];
#pragma unroll
    for (int j = 0; j < 12; j++) {
        float v = s2s[t * 12 + j] + sw[j];
#pragma unroll
        for (int k = 0; k < 32; k++) v += hh[k] * sw[12 + j * 32 + k];
        h2[j] = fmaxf(v, 0.0f);
    }
#pragma unroll
    for (int j = 0; j < 4; j++) {
        float v = sw[524 + j];
#pragma unroll
        for (int k = 0; k < 32; k++)
            v += ax[k] * sw[396 + j * 32 + k] + hh[k] * sw[528 + j * 32 + k];
        h2[12 + j] = fmaxf(v, 0.0f);
    }

    float t3[8];
#pragma unroll
    for (int j = 0; j < 8; j++) {
        float v = sw[784 + j];
#pragma unroll
        for (int k = 0; k < 16; k++) v += h2[k] * sw[656 + j * 16 + k];
        t3[j] = fmaxf(v, 0.0f);
    }
    float t4[5];
#pragma unroll
    for (int j = 0; j < 5; j++) {
        float v = sw[832 + j];
#pragma unroll
        for (int k = 0; k < 8; k++) v += t3[k] * sw[792 + j * 8 + k];
        t4[j] = fmaxf(v, 0.0f);
    }
    float o = sw[842];
#pragma unroll
    for (int k = 0; k < 5; k++) o += t4[k] * sw[837 + k];
    out[i] = o;
}

extern "C" void kernel_launch(void* const* d_in, const int* in_sizes, int n_in,
                              void* d_out, int out_size, void* d_ws, size_t ws_size,
                              hipStream_t stream) {
    const float* x     = (const float*)d_in[0];
    const int*   ei    = (const int*)d_in[1];
    const float* norm  = (const float*)d_in[2];
    const float* w1m_l = (const float*)d_in[3];
    const float* b1m   = (const float*)d_in[4];
    const float* w1m_r = (const float*)d_in[5];
    const float* w1x_l = (const float*)d_in[6];
    const float* b1x   = (const float*)d_in[7];
    const float* w1x_r = (const float*)d_in[8];
    const float* w2m_l = (const float*)d_in[9];
    const float* b2m   = (const float*)d_in[10];
    const float* w2m_r = (const float*)d_in[11];
    const float* w2x_l = (const float*)d_in[12];
    const float* b2x   = (const float*)d_in[13];
    const float* w2x_r = (const float*)d_in[14];
    const float* w3    = (const float*)d_in[15];
    const float* b3    = (const float*)d_in[16];
    const float* w4    = (const float*)d_in[17];
    const float* b4    = (const float*)d_in[18];
    const float* w5    = (const float*)d_in[19];
    const float* b5    = (const float*)d_in[20];
    float* out = (float*)d_out;

    // workspace layout (~43.3 MB, all merge-free: no agg buffers)
    char* ws = (char*)d_ws;
    int2*  ebuf = (int2*)ws;                              // 25.6 MB
    float* h1   = (float*)(ws + (size_t)N_EDGES * 8);     // 32*NPAD = 12.8 MB
    float* z2   = h1 + (size_t)32 * NPAD;                 // 12*NPAD =  4.8 MB
    int*   total    = (int*)(z2 + (size_t)12 * NPAD);     // NCELL
    int*   cellBase = total + NCELL;                      // NCELL+1
    int*   cursor   = cellBase + NCELL + 1;               // NCELL

    hipMemsetAsync(total, 0, NCELL * sizeof(int), stream);

    k1_count  <<<K13_BLOCKS, 256, 0, stream>>>(ei, total);
    k2_scan   <<<1, 1024, 0, stream>>>(total, cellBase, cursor);
    k3_scatter<<<K13_BLOCKS, 256, 0, stream>>>(ei, norm, cursor, ebuf);
    k4_fused  <<<NBUCK, 256, 0, stream>>>((const float2*)x, ebuf, cellBase,
                                          w1m_l, b1m, w1m_r, w1x_l, b1x, w1x_r,
                                          w2m_l, h1, z2);
    k5_fused  <<<NBUCK, 256, 0, stream>>>(h1, z2, ebuf, cellBase,
                                          b2m, w2m_r, w2x_l, b2x, w2x_r,
                                          w3, b3, w4, b4, w5, b5, out);
}

// Round 7
// 555.205 us; speedup vs baseline: 1.1734x; 1.1734x over previous
//
#include <hip/hip_runtime.h>
#include <cstdint>

#define N_NODES 100000
#define N_EDGES 3200000
#define BSZ     64                // dst nodes per bucket (single-owner, merge-free)
#define NBUCK   1563              // ceil(N_NODES / 64)
#define NPAD    (NBUCK * BSZ)     // 100032
#define K13_BLOCKS 256
#define K13_CHUNK  12500          // 256 * 12500 = 3.2M exactly

// ---- float <-> order-preserving unsigned (signed-float max via uint max) ----
__device__ __forceinline__ unsigned flipf(float f) {
    unsigned u = __float_as_uint(f);
    return (u & 0x80000000u) ? ~u : (u | 0x80000000u);
}
__device__ __forceinline__ float unflipf(unsigned v) {
    unsigned u = (v & 0x80000000u) ? (v & 0x7FFFFFFFu) : ~v;
    return __uint_as_float(u);
}

// ---------------- K1: per-bucket edge counts (dst only) ----------------
__global__ __launch_bounds__(256) void k1_count(const int* __restrict__ dst,
                                                int* __restrict__ total) {
    __shared__ int hist[NBUCK];              // 6.3 KB
    for (int t = threadIdx.x; t < NBUCK; t += 256) hist[t] = 0;
    __syncthreads();
    int e0 = blockIdx.x * K13_CHUNK;
    for (int k = threadIdx.x; k < K13_CHUNK; k += 256)
        atomicAdd(&hist[dst[e0 + k] >> 6], 1);
    __syncthreads();
    for (int t = threadIdx.x; t < NBUCK; t += 256) {
        int c = hist[t];
        if (c) atomicAdd(&total[t], c);
    }
}

// ---------------- K2: exclusive scan over NBUCK -> bucketBase, cursor ----------------
__global__ __launch_bounds__(512) void k2_scan(const int* __restrict__ total,
                                               int* __restrict__ bucketBase,
                                               int* __restrict__ cursor) {
    __shared__ int part[512];
    int t = threadIdx.x;
    int base = t * 4;
    int v0 = (base     < NBUCK) ? total[base]     : 0;
    int v1 = (base + 1 < NBUCK) ? total[base + 1] : 0;
    int v2 = (base + 2 < NBUCK) ? total[base + 2] : 0;
    int v3 = (base + 3 < NBUCK) ? total[base + 3] : 0;
    int s = v0 + v1 + v2 + v3;
    part[t] = s;
    __syncthreads();
    for (int off = 1; off < 512; off <<= 1) {
        int u = (t >= off) ? part[t - off] : 0;
        __syncthreads();
        part[t] += u;
        __syncthreads();
    }
    int ex = part[t] - s;
    if (base     < NBUCK) { bucketBase[base]     = ex;              cursor[base]     = ex; }
    if (base + 1 < NBUCK) { bucketBase[base + 1] = ex + v0;         cursor[base + 1] = ex + v0; }
    if (base + 2 < NBUCK) { bucketBase[base + 2] = ex + v0 + v1;    cursor[base + 2] = ex + v0 + v1; }
    if (base + 3 < NBUCK) { bucketBase[base + 3] = ex + v0 + v1 + v2; cursor[base + 3] = ex + v0 + v1 + v2; }
    if (t == 511) bucketBase[NBUCK] = part[511];
}

// ---------------- K3: scatter edges into bucket-contiguous packed records ----------------
// record: int2 { (src<<6) | (dst&63), bits(norm) }
__global__ __launch_bounds__(256) void k3_scatter(const int* __restrict__ ei,
                                                  const float* __restrict__ norm,
                                                  int* __restrict__ cursor,
                                                  int2* __restrict__ ebuf) {
    __shared__ int hist[NBUCK];              // 6.3 KB
    __shared__ int lcur[NBUCK];              // 6.3 KB
    for (int t = threadIdx.x; t < NBUCK; t += 256) hist[t] = 0;
    __syncthreads();
    int e0 = blockIdx.x * K13_CHUNK;
    for (int k = threadIdx.x; k < K13_CHUNK; k += 256)
        atomicAdd(&hist[ei[N_EDGES + e0 + k] >> 6], 1);
    __syncthreads();
    for (int t = threadIdx.x; t < NBUCK; t += 256) {
        int c = hist[t];
        lcur[t] = c ? atomicAdd(&cursor[t], c) : 0;
    }
    __syncthreads();
    for (int k = threadIdx.x; k < K13_CHUNK; k += 256) {
        int e = e0 + k;
        int s = ei[e];
        int d = ei[N_EDGES + e];
        float w = norm[e];
        int r = atomicAdd(&lcur[d >> 6], 1);
        ebuf[r] = make_int2((s << 6) | (d & 63), __float_as_int(w));
    }
}

// -------- K4: layer-1 aggregation (LDS, merge-free) -> packed (x,a,m) + z2 --------
// sw layout: w1m_l[0..48) b1m[48..72) w1m_r[72..120) w1x_l[120..136) b1x[136..144)
//            w1x_r[144..160) w2m_l[160..544)
__global__ __launch_bounds__(256) void k4_fused(
        const float2* __restrict__ x, const int2* __restrict__ ebuf,
        const int* __restrict__ bucketBase,
        const float* __restrict__ w1m_l, const float* __restrict__ b1m,
        const float* __restrict__ w1m_r,
        const float* __restrict__ w1x_l, const float* __restrict__ b1x,
        const float* __restrict__ w1x_r,
        const float* __restrict__ w2m_l,
        float* __restrict__ packed, float* __restrict__ z2) {
    __shared__ float sw[544];
    __shared__ float    s_sum[2 * BSZ];
    __shared__ unsigned s_max[2 * BSZ];
    for (int t = threadIdx.x; t < 544; t += 256) {
        float v;
        if (t < 48)       v = w1m_l[t];
        else if (t < 72)  v = b1m[t - 48];
        else if (t < 120) v = w1m_r[t - 72];
        else if (t < 136) v = w1x_l[t - 120];
        else if (t < 144) v = b1x[t - 136];
        else if (t < 160) v = w1x_r[t - 144];
        else              v = w2m_l[t - 160];
        sw[t] = v;
    }
    if (threadIdx.x < 2 * BSZ) { s_sum[threadIdx.x] = 0.0f; s_max[threadIdx.x] = 0u; }
    __syncthreads();

    int b = blockIdx.x;
    int beg = bucketBase[b], end = bucketBase[b + 1];

    int e = beg + threadIdx.x;
    for (; e + 768 < end; e += 1024) {
        int2 r0 = ebuf[e], r1 = ebuf[e + 256], r2 = ebuf[e + 512], r3 = ebuf[e + 768];
        float2 x0 = x[r0.x >> 6], x1 = x[r1.x >> 6], x2 = x[r2.x >> 6], x3 = x[r3.x >> 6];
        float w0 = __int_as_float(r0.y), w1 = __int_as_float(r1.y);
        float w2 = __int_as_float(r2.y), w3 = __int_as_float(r3.y);
        int l0 = (r0.x & 63) * 2, l1 = (r1.x & 63) * 2, l2 = (r2.x & 63) * 2, l3 = (r3.x & 63) * 2;
        atomicAdd(&s_sum[l0],     x0.x * w0); atomicAdd(&s_sum[l0 + 1], x0.y * w0);
        atomicAdd(&s_sum[l1],     x1.x * w1); atomicAdd(&s_sum[l1 + 1], x1.y * w1);
        atomicAdd(&s_sum[l2],     x2.x * w2); atomicAdd(&s_sum[l2 + 1], x2.y * w2);
        atomicAdd(&s_sum[l3],     x3.x * w3); atomicAdd(&s_sum[l3 + 1], x3.y * w3);
        atomicMax(&s_max[l0],     flipf(x0.x)); atomicMax(&s_max[l0 + 1], flipf(x0.y));
        atomicMax(&s_max[l1],     flipf(x1.x)); atomicMax(&s_max[l1 + 1], flipf(x1.y));
        atomicMax(&s_max[l2],     flipf(x2.x)); atomicMax(&s_max[l2 + 1], flipf(x2.y));
        atomicMax(&s_max[l3],     flipf(x3.x)); atomicMax(&s_max[l3 + 1], flipf(x3.y));
    }
    for (; e < end; e += 256) {
        int2 r = ebuf[e];
        float2 xs = x[r.x >> 6];
        float w = __int_as_float(r.y);
        int l = (r.x & 63) * 2;
        atomicAdd(&s_sum[l],     xs.x * w); atomicAdd(&s_sum[l + 1], xs.y * w);
        atomicMax(&s_max[l],     flipf(xs.x)); atomicMax(&s_max[l + 1], flipf(xs.y));
    }
    __syncthreads();

    // epilogue for this block's 64 nodes: write packed row + z2 row
    int t = threadIdx.x;
    if (t >= BSZ) return;
    int i = b * BSZ + t;
    if (i >= N_NODES) return;

    float2 xi = x[i];
    float a0 = s_sum[2 * t], a1 = s_sum[2 * t + 1];
    unsigned m0u = s_max[2 * t], m1u = s_max[2 * t + 1];
    float m0 = m0u ? unflipf(m0u) : 0.0f;   // 0 sentinel == empty segment -> 0
    float m1 = m1u ? unflipf(m1u) : 0.0f;

    float4* pk = (float4*)(packed + (size_t)i * 8);
    pk[0] = make_float4(xi.x, xi.y, a0, a1);
    pk[1] = make_float4(m0, m1, 0.0f, 0.0f);

    float hh[32];
#pragma unroll
    for (int k = 0; k < 24; k++) {
        float v = sw[48 + k] + sw[2 * k] * a0 + sw[2 * k + 1] * a1
                + sw[72 + 2 * k] * xi.x + sw[72 + 2 * k + 1] * xi.y;
        hh[k] = fmaxf(v, 0.0f);
    }
#pragma unroll
    for (int k = 0; k < 8; k++) {
        float v = sw[136 + k] + sw[120 + 2 * k] * m0 + sw[120 + 2 * k + 1] * m1
                + sw[144 + 2 * k] * xi.x + sw[144 + 2 * k + 1] * xi.y;
        hh[24 + k] = fmaxf(v, 0.0f);
    }

    float zz[12];
#pragma unroll
    for (int j = 0; j < 12; j++) {
        float v = 0.0f;
#pragma unroll
        for (int k = 0; k < 32; k++) v += hh[k] * sw[160 + j * 32 + k];
        zz[j] = v;
    }
    float4* z2v = (float4*)(z2 + (size_t)i * 12);
    z2v[0] = make_float4(zz[0], zz[1], zz[2], zz[3]);
    z2v[1] = make_float4(zz[4], zz[5], zz[6], zz[7]);
    z2v[2] = make_float4(zz[8], zz[9], zz[10], zz[11]);
}

// -------- K5: layer-2 aggregation (merge-free, L2-resident gathers) + node2 + MLP --------
// sum phase gathers z2 (4.8 MB); max phase gathers packed (3.2 MB) and recomputes
// h1 features in-lane (5 FMA). sw layout:
//   [0..160)   layer1: w1m_l[0..48) b1m[48..72) w1m_r[72..120) w1x_l[120..136)
//              b1x[136..144) w1x_r[144..160)
//   [160..1003) layer2+MLP: b2m[160..172) w2m_r[172..556) w2x_l[556..684) b2x[684..688)
//              w2x_r[688..816) w3[816..944) b3[944..952) w4[952..992) b4[992..997)
//              w5[997..1002) b5[1002]
__global__ __launch_bounds__(256) void k5_fused(
        const float* __restrict__ packed, const float* __restrict__ z2g,
        const int2* __restrict__ ebuf, const int* __restrict__ bucketBase,
        const float* __restrict__ w1m_l, const float* __restrict__ b1m,
        const float* __restrict__ w1m_r,
        const float* __restrict__ w1x_l, const float* __restrict__ b1x,
        const float* __restrict__ w1x_r,
        const float* __restrict__ b2m, const float* __restrict__ w2m_r,
        const float* __restrict__ w2x_l, const float* __restrict__ b2x,
        const float* __restrict__ w2x_r,
        const float* __restrict__ w3, const float* __restrict__ b3,
        const float* __restrict__ w4, const float* __restrict__ b4,
        const float* __restrict__ w5, const float* __restrict__ b5,
        float* __restrict__ out) {
    __shared__ float sw[1003];               // 4 KB
    __shared__ unsigned s2x[BSZ * 32];       // 8 KB
    __shared__ float    s2s[BSZ * 12];       // 3 KB
    for (int t = threadIdx.x; t < 1003; t += 256) {
        float v;
        if (t < 48)        v = w1m_l[t];
        else if (t < 72)   v = b1m[t - 48];
        else if (t < 120)  v = w1m_r[t - 72];
        else if (t < 136)  v = w1x_l[t - 120];
        else if (t < 144)  v = b1x[t - 136];
        else if (t < 160)  v = w1x_r[t - 144];
        else if (t < 172)  v = b2m[t - 160];
        else if (t < 556)  v = w2m_r[t - 172];
        else if (t < 684)  v = w2x_l[t - 556];
        else if (t < 688)  v = b2x[t - 684];
        else if (t < 816)  v = w2x_r[t - 688];
        else if (t < 944)  v = w3[t - 816];
        else if (t < 952)  v = b3[t - 944];
        else if (t < 992)  v = w4[t - 952];
        else if (t < 997)  v = b4[t - 992];
        else if (t < 1002) v = w5[t - 997];
        else               v = b5[0];
        sw[t] = v;
    }
    for (int t = threadIdx.x; t < BSZ * 32; t += 256) s2x[t] = 0u;
    for (int t = threadIdx.x; t < BSZ * 12; t += 256) s2s[t] = 0.0f;
    __syncthreads();

    int b = blockIdx.x;
    int beg = bucketBase[b], end = bucketBase[b + 1];

    // per-lane layer-1 feature constants for the max phase (f = lane & 31)
    int f32 = threadIdx.x & 31;
    float c0, c1, c2, c3, c4;
    int goff;                                // float2 offset of (g0,g1) in packed row
    if (f32 < 24) {
        c0 = sw[48 + f32];  c1 = sw[2 * f32];       c2 = sw[2 * f32 + 1];
        c3 = sw[72 + 2 * f32]; c4 = sw[72 + 2 * f32 + 1];
        goff = 1;                            // (a0,a1)
    } else {
        int g = f32 - 24;
        c0 = sw[136 + g];   c1 = sw[120 + 2 * g];   c2 = sw[120 + 2 * g + 1];
        c3 = sw[144 + 2 * g]; c4 = sw[144 + 2 * g + 1];
        goff = 2;                            // (m0,m1)
    }

    // ---- phase 1: weighted-sum aggregation (gather z2, 16 lanes/edge) ----
    {
        int f  = threadIdx.x & 15;
        int eg = threadIdx.x >> 4;           // 16 edge-groups
        int e = beg + eg;
        for (; e + 48 < end; e += 64) {
            int2 r0 = ebuf[e], r1 = ebuf[e + 16], r2 = ebuf[e + 32], r3 = ebuf[e + 48];
            if (f < 12) {
                float z0 = z2g[(size_t)(r0.x >> 6) * 12 + f];
                float z1 = z2g[(size_t)(r1.x >> 6) * 12 + f];
                float z2v = z2g[(size_t)(r2.x >> 6) * 12 + f];
                float z3 = z2g[(size_t)(r3.x >> 6) * 12 + f];
                atomicAdd(&s2s[(r0.x & 63) * 12 + f], z0  * __int_as_float(r0.y));
                atomicAdd(&s2s[(r1.x & 63) * 12 + f], z1  * __int_as_float(r1.y));
                atomicAdd(&s2s[(r2.x & 63) * 12 + f], z2v * __int_as_float(r2.y));
                atomicAdd(&s2s[(r3.x & 63) * 12 + f], z3  * __int_as_float(r3.y));
            }
        }
        for (; e < end; e += 16) {
            int2 r = ebuf[e];
            if (f < 12) {
                float z = z2g[(size_t)(r.x >> 6) * 12 + f];
                atomicAdd(&s2s[(r.x & 63) * 12 + f], z * __int_as_float(r.y));
            }
        }
    }

    // ---- phase 2: max aggregation (gather packed 32B row, recompute h1_f) ----
    {
        const float2* pk = (const float2*)packed;
        int eg = threadIdx.x >> 5;           // 8 edge-groups
        int e = beg + eg;
        for (; e + 24 < end; e += 32) {
            int2 r0 = ebuf[e], r1 = ebuf[e + 8], r2 = ebuf[e + 16], r3 = ebuf[e + 24];
            int s0 = r0.x >> 6, s1 = r1.x >> 6, s2 = r2.x >> 6, s3 = r3.x >> 6;
            float2 xa = pk[(size_t)s0 * 4];     float2 ga = pk[(size_t)s0 * 4 + goff];
            float2 xb = pk[(size_t)s1 * 4];     float2 gb = pk[(size_t)s1 * 4 + goff];
            float2 xc = pk[(size_t)s2 * 4];     float2 gc = pk[(size_t)s2 * 4 + goff];
            float2 xd = pk[(size_t)s3 * 4];     float2 gd = pk[(size_t)s3 * 4 + goff];
            float v0 = fmaxf(c0 + c1 * ga.x + c2 * ga.y + c3 * xa.x + c4 * xa.y, 0.0f);
            float v1 = fmaxf(c0 + c1 * gb.x + c2 * gb.y + c3 * xb.x + c4 * xb.y, 0.0f);
            float v2 = fmaxf(c0 + c1 * gc.x + c2 * gc.y + c3 * xc.x + c4 * xc.y, 0.0f);
            float v3 = fmaxf(c0 + c1 * gd.x + c2 * gd.y + c3 * xd.x + c4 * xd.y, 0.0f);
            atomicMax(&s2x[(r0.x & 63) * 32 + f32], __float_as_uint(v0));
            atomicMax(&s2x[(r1.x & 63) * 32 + f32], __float_as_uint(v1));
            atomicMax(&s2x[(r2.x & 63) * 32 + f32], __float_as_uint(v2));
            atomicMax(&s2x[(r3.x & 63) * 32 + f32], __float_as_uint(v3));
        }
        for (; e < end; e += 8) {
            int2 r = ebuf[e];
            int s = r.x >> 6;
            float2 xv = pk[(size_t)s * 4];
            float2 gv = pk[(size_t)s * 4 + goff];
            float v = fmaxf(c0 + c1 * gv.x + c2 * gv.y + c3 * xv.x + c4 * xv.y, 0.0f);
            atomicMax(&s2x[(r.x & 63) * 32 + f32], __float_as_uint(v));
        }
    }
    __syncthreads();

    // ---- epilogue: node2 + MLP for this block's 64 nodes ----
    int t = threadIdx.x;
    if (t >= BSZ) return;
    int i = b * BSZ + t;
    if (i >= N_NODES) return;

    const float4* pk4 = (const float4*)(packed + (size_t)i * 8);
    float4 p0 = pk4[0], p1 = pk4[1];
    float xi0 = p0.x, xi1 = p0.y, a0 = p0.z, a1 = p0.w, m0 = p1.x, m1 = p1.y;

    float hh[32];
#pragma unroll
    for (int k = 0; k < 24; k++) {
        float v = sw[48 + k] + sw[2 * k] * a0 + sw[2 * k + 1] * a1
                + sw[72 + 2 * k] * xi0 + sw[72 + 2 * k + 1] * xi1;
        hh[k] = fmaxf(v, 0.0f);
    }
#pragma unroll
    for (int k = 0; k < 8; k++) {
        float v = sw[136 + k] + sw[120 + 2 * k] * m0 + sw[120 + 2 * k + 1] * m1
                + sw[144 + 2 * k] * xi0 + sw[144 + 2 * k + 1] * xi1;
        hh[24 + k] = fmaxf(v, 0.0f);
    }

    float ax[32];
#pragma unroll
    for (int k = 0; k < 32; k++) ax[k] = __uint_as_float(s2x[t * 32 + k]);

    float h2[16];
#pragma unroll
    for (int j = 0; j < 12; j++) {
        float v = s2s[t * 12 + j] + sw[160 + j];
#pragma unroll
        for (int k = 0; k < 32; k++) v += hh[k] * sw[172 + j * 32 + k];
        h2[j] = fmaxf(v, 0.0f);
    }
#pragma unroll
    for (int j = 0; j < 4; j++) {
        float v = sw[684 + j];
#pragma unroll
        for (int k = 0; k < 32; k++)
            v += ax[k] * sw[556 + j * 32 + k] + hh[k] * sw[688 + j * 32 + k];
        h2[12 + j] = fmaxf(v, 0.0f);
    }

    float t3[8];
#pragma unroll
    for (int j = 0; j < 8; j++) {
        float v = sw[944 + j];
#pragma unroll
        for (int k = 0; k < 16; k++) v += h2[k] * sw[816 + j * 16 + k];
        t3[j] = fmaxf(v, 0.0f);
    }
    float t4[5];
#pragma unroll
    for (int j = 0; j < 5; j++) {
        float v = sw[992 + j];
#pragma unroll
        for (int k = 0; k < 8; k++) v += t3[k] * sw[952 + j * 8 + k];
        t4[j] = fmaxf(v, 0.0f);
    }
    float o = sw[1002];
#pragma unroll
    for (int k = 0; k < 5; k++) o += t4[k] * sw[997 + k];
    out[i] = o;
}

extern "C" void kernel_launch(void* const* d_in, const int* in_sizes, int n_in,
                              void* d_out, int out_size, void* d_ws, size_t ws_size,
                              hipStream_t stream) {
    const float* x     = (const float*)d_in[0];
    const int*   ei    = (const int*)d_in[1];
    const float* norm  = (const float*)d_in[2];
    const float* w1m_l = (const float*)d_in[3];
    const float* b1m   = (const float*)d_in[4];
    const float* w1m_r = (const float*)d_in[5];
    const float* w1x_l = (const float*)d_in[6];
    const float* b1x   = (const float*)d_in[7];
    const float* w1x_r = (const float*)d_in[8];
    const float* w2m_l = (const float*)d_in[9];
    const float* b2m   = (const float*)d_in[10];
    const float* w2m_r = (const float*)d_in[11];
    const float* w2x_l = (const float*)d_in[12];
    const float* b2x   = (const float*)d_in[13];
    const float* w2x_r = (const float*)d_in[14];
    const float* w3    = (const float*)d_in[15];
    const float* b3    = (const float*)d_in[16];
    const float* w4    = (const float*)d_in[17];
    const float* b4    = (const float*)d_in[18];
    const float* w5    = (const float*)d_in[19];
    const float* b5    = (const float*)d_in[20];
    float* out = (float*)d_out;

    // workspace (~33.7 MB)
    char* ws = (char*)d_ws;
    int2*  ebuf   = (int2*)ws;                              // 25.6 MB
    float* packed = (float*)(ws + (size_t)N_EDGES * 8);     //  8*NPAD = 3.2 MB
    float* z2     = packed + (size_t)8 * NPAD;              // 12*NPAD = 4.8 MB
    int*   total      = (int*)(z2 + (size_t)12 * NPAD);     // NBUCK
    int*   bucketBase = total + NBUCK;                      // NBUCK+1
    int*   cursor     = bucketBase + NBUCK + 1;             // NBUCK

    hipMemsetAsync(total, 0, NBUCK * sizeof(int), stream);

    k1_count  <<<K13_BLOCKS, 256, 0, stream>>>(ei + N_EDGES, total);
    k2_scan   <<<1, 512, 0, stream>>>(total, bucketBase, cursor);
    k3_scatter<<<K13_BLOCKS, 256, 0, stream>>>(ei, norm, cursor, ebuf);
    k4_fused  <<<NBUCK, 256, 0, stream>>>((const float2*)x, ebuf, bucketBase,
                                          w1m_l, b1m, w1m_r, w1x_l, b1x, w1x_r,
                                          w2m_l, packed, z2);
    k5_fused  <<<NBUCK, 256, 0, stream>>>(packed, z2, ebuf, bucketBase,
                                          w1m_l, b1m, w1m_r, w1x_l, b1x, w1x_r,
                                          b2m, w2m_r, w2x_l, b2x, w2x_r,
                                          w3, b3, w4, b4, w5, b5, out);
}